// Round 1
// baseline (243.849 us; speedup 1.0000x reference)
//
#include <hip/hip_runtime.h>
#include <math.h>

#define NUM_E 8
#define DIM 4096
#define THREADS 256
#define WAVES (THREADS / 64)
#define VEC_ITERS (DIM / (THREADS * 4))   // 4

__global__ __launch_bounds__(THREADS) void gate_fused_kernel(
    const float* __restrict__ x,        // [B, D]
    const float* __restrict__ experts,  // [B, NUM, D]
    const float* __restrict__ W,        // [NUM, D]
    float* __restrict__ out)            // [B, D]
{
    const int b    = blockIdx.x;
    const int t    = threadIdx.x;
    const int lane = t & 63;
    const int wave = t >> 6;

    const float* __restrict__ xrow = x + (size_t)b * DIM;
    const float* __restrict__ erow = experts + (size_t)b * NUM_E * DIM;
    float* __restrict__ orow = out + (size_t)b * DIM;

    // ---- Phase 1: partial dot products x[b,:] . W[n,:] ----
    float p[NUM_E];
#pragma unroll
    for (int n = 0; n < NUM_E; ++n) p[n] = 0.0f;

#pragma unroll
    for (int i = 0; i < VEC_ITERS; ++i) {
        const int d = (i * THREADS + t) * 4;
        const float4 xv = *reinterpret_cast<const float4*>(xrow + d);
#pragma unroll
        for (int n = 0; n < NUM_E; ++n) {
            const float4 wv = *reinterpret_cast<const float4*>(W + n * DIM + d);
            p[n] += xv.x * wv.x + xv.y * wv.y + xv.z * wv.z + xv.w * wv.w;
        }
    }

    // ---- wave-level butterfly reduce (64 lanes) ----
#pragma unroll
    for (int n = 0; n < NUM_E; ++n) {
#pragma unroll
        for (int off = 32; off > 0; off >>= 1)
            p[n] += __shfl_down(p[n], off, 64);
    }

    __shared__ float red[WAVES * NUM_E];
    if (lane == 0) {
#pragma unroll
        for (int n = 0; n < NUM_E; ++n) red[wave * NUM_E + n] = p[n];
    }
    __syncthreads();

    // ---- every thread computes the 8-wide softmax redundantly ----
    float wgt[NUM_E];
#pragma unroll
    for (int n = 0; n < NUM_E; ++n) {
        float s = 0.0f;
#pragma unroll
        for (int w2 = 0; w2 < WAVES; ++w2) s += red[w2 * NUM_E + n];
        wgt[n] = s;
    }
    float m = wgt[0];
#pragma unroll
    for (int n = 1; n < NUM_E; ++n) m = fmaxf(m, wgt[n]);
    float sum = 0.0f;
#pragma unroll
    for (int n = 0; n < NUM_E; ++n) {
        wgt[n] = __expf(wgt[n] - m);
        sum += wgt[n];
    }
    const float inv = 1.0f / sum;
#pragma unroll
    for (int n = 0; n < NUM_E; ++n) wgt[n] *= inv;

    // ---- Phase 2: weighted combine over experts ----
#pragma unroll
    for (int i = 0; i < VEC_ITERS; ++i) {
        const int d = (i * THREADS + t) * 4;
        float4 acc = make_float4(0.f, 0.f, 0.f, 0.f);
#pragma unroll
        for (int n = 0; n < NUM_E; ++n) {
            const float4 ev = *reinterpret_cast<const float4*>(erow + (size_t)n * DIM + d);
            acc.x += wgt[n] * ev.x;
            acc.y += wgt[n] * ev.y;
            acc.z += wgt[n] * ev.z;
            acc.w += wgt[n] * ev.w;
        }
        *reinterpret_cast<float4*>(orow + d) = acc;
    }
}

extern "C" void kernel_launch(void* const* d_in, const int* in_sizes, int n_in,
                              void* d_out, int out_size, void* d_ws, size_t ws_size,
                              hipStream_t stream) {
    const float* x       = (const float*)d_in[0];
    const float* experts = (const float*)d_in[1];
    const float* W       = (const float*)d_in[2];
    float* out           = (float*)d_out;

    const int B = in_sizes[0] / DIM;   // 8192

    gate_fused_kernel<<<B, THREADS, 0, stream>>>(x, experts, W, out);
}